// Round 8
// baseline (189.374 us; speedup 1.0000x reference)
//
#include <hip/hip_runtime.h>

typedef _Float16 f16;
typedef _Float16 f16x2 __attribute__((ext_vector_type(2)));
typedef _Float16 f16x4 __attribute__((ext_vector_type(4)));
typedef _Float16 f16x8 __attribute__((ext_vector_type(8)));
typedef float f32x4v __attribute__((ext_vector_type(4)));

#define AS1 __attribute__((address_space(1)))
#define AS3 __attribute__((address_space(3)))

// async global->LDS, 16B per lane; LDS dest = wave-uniform base + lane*16
__device__ __forceinline__ void gload_lds16(const f16* g, f16* l) {
  __builtin_amdgcn_global_load_lds((const AS1 unsigned int*)g,
                                   (AS3 unsigned int*)l, 16, 0, 0);
}

// ---------------------------------------------------------------------------
// prep: fp32 -> fp16 conversions, 8 elems/thread (2x float4 -> 1x f16x8).
// ---------------------------------------------------------------------------
__global__ __launch_bounds__(256) void prep_kernel(
    const float* __restrict__ Q_seq, const float* __restrict__ K_seq,
    const float* __restrict__ V_seq,
    const float* __restrict__ Wq, const float* __restrict__ Wk,
    const float* __restrict__ Wv,
    f16* __restrict__ Qb, f16* __restrict__ Kb, f16* __restrict__ Vb,
    f16* __restrict__ Wqb, f16* __restrict__ Wkb, f16* __restrict__ Wvb)
{
  const long long g = (long long)blockIdx.x * 256 + threadIdx.x;
  const float* s;
  f16* d;
  if (g < 524288) {
    s = Q_seq + g * 8; d = Qb + g * 8;
  } else if (g < 2621440) {
    long long e = (g - 524288) * 8; s = K_seq + e; d = Kb + e;
  } else if (g < 4718592) {
    long long e = (g - 2621440) * 8; s = V_seq + e; d = Vb + e;
  } else if (g < 4849664) {
    long long e = (g - 4718592) * 8; s = Wq + e; d = Wqb + e;
  } else if (g < 4980736) {
    long long e = (g - 4849664) * 8; s = Wk + e; d = Wkb + e;
  } else {
    long long e = (g - 4980736) * 8; s = Wv + e; d = Wvb + e;
  }
  float4 v0 = *(const float4*)s;
  float4 v1 = *(const float4*)(s + 4);
  f16x8 o;
  o[0] = (f16)v0.x; o[1] = (f16)v0.y; o[2] = (f16)v0.z; o[3] = (f16)v0.w;
  o[4] = (f16)v1.x; o[5] = (f16)v1.y; o[6] = (f16)v1.z; o[7] = (f16)v1.w;
  *(f16x8*)d = o;
}

// ---------------------------------------------------------------------------
// 256x256 tile GEMM, BK=64, 8 waves (2M x 4N), double-buffered LDS (128 KiB).
// T2: XOR-swizzled LDS via pre-swizzled global source (linear LDS dest).
// T3/T4: counted vmcnt(8) at tile top; K-tile split into 4 fine phases
//   (kstep x i-half), each {4-8 ds_read -> barrier -> lgkm(0) -> 16 MFMA ->
//   barrier} so LDS service overlaps MFMA across waves (m201 schedule).
// T5: setprio(1) around each 16-MFMA cluster.
// Staging: 2 tiles ahead, issued in phase 3 after the certification barrier.
// ---------------------------------------------------------------------------
__device__ __forceinline__ void gemm_tile_256(
    const f16* __restrict__ A, const f16* __restrict__ W,
    const float* __restrict__ bias, f16* __restrict__ C,
    int m0, int n0, int rowShift, int outStride, int rowOff,
    f16* sbuf)
{
  const int t = threadIdx.x;
  const int w = t >> 6, lane = t & 63;
  const int wr = w >> 2, wc = w & 3;        // 2 x 4 wave grid
  const int fr = lane & 15, g = lane >> 4;  // fragment row / k-group
  const int lrow = lane >> 3;               // staging: row-in-8 block
  const int kgr = (lane & 7) ^ lrow;        // staging: pre-swizzled k-granule

  const f16* aSrc[4];
  const f16* bSrc[4];
#pragma unroll
  for (int s = 0; s < 4; ++s) {
    aSrc[s] = A + (long long)(m0 + (w * 4 + s) * 8 + lrow) * 1024 + kgr * 8;
    bSrc[s] = W + (long long)(n0 + (w * 4 + s) * 8 + lrow) * 1024 + kgr * 8;
  }

#define STAGE(tile)                                                          \
  {                                                                          \
    f16* ab_ = sbuf + (((tile) & 1) << 15);                                  \
    const int ko_ = (tile) * 64;                                             \
    _Pragma("unroll") for (int s = 0; s < 4; ++s)                            \
        gload_lds16(aSrc[s] + ko_, ab_ + (w * 4 + s) * 512);                 \
    _Pragma("unroll") for (int s = 0; s < 4; ++s)                            \
        gload_lds16(bSrc[s] + ko_, ab_ + 16384 + (w * 4 + s) * 512);         \
  }

  // fragment read offsets (f16 units), granule XOR-swizzled
  const int gk0 = ((0 + g) ^ (fr & 7)) * 8;   // k-half 0
  const int gk1 = ((4 + g) ^ (fr & 7)) * 8;   // k-half 1
  const int aoff = (wr * 128 + fr) * 64;
  const int boff = (wc * 64 + fr) * 64;

  f32x4v acc[8][4];
#pragma unroll
  for (int i = 0; i < 8; ++i)
#pragma unroll
    for (int j = 0; j < 4; ++j) acc[i][j] = (f32x4v){0.f, 0.f, 0.f, 0.f};

  STAGE(0);
  STAGE(1);

#define RD_A(dst, ihalf, gk)                                                 \
  _Pragma("unroll") for (int ii = 0; ii < 4; ++ii)                           \
      dst[ii] = *(const f16x8*)(ab + aoff + ((ihalf) * 4 + ii) * 1024 + (gk));
#define RD_B(dst, gk)                                                        \
  _Pragma("unroll") for (int j = 0; j < 4; ++j)                              \
      dst[j] = *(const f16x8*)(bb + boff + j * 1024 + (gk));
#define MFMA16(afr, bfr, ihalf)                                              \
  __builtin_amdgcn_s_setprio(1);                                             \
  _Pragma("unroll") for (int ii = 0; ii < 4; ++ii)                           \
      _Pragma("unroll") for (int j = 0; j < 4; ++j)                          \
          acc[(ihalf) * 4 + ii][j] = __builtin_amdgcn_mfma_f32_16x16x32_f16( \
              afr[ii], bfr[j], acc[(ihalf) * 4 + ii][j], 0, 0, 0);           \
  __builtin_amdgcn_s_setprio(0);

  for (int tt = 0; tt < 16; ++tt) {
    // tile tt resident: my 8 oldest loads (tile tt) done; barrier -> all waves
    if (tt < 15) {
      asm volatile("s_waitcnt vmcnt(8)" ::: "memory");
    } else {
      asm volatile("s_waitcnt vmcnt(0)" ::: "memory");
    }
    __builtin_amdgcn_sched_barrier(0);
    __builtin_amdgcn_s_barrier();
    __builtin_amdgcn_sched_barrier(0);

    const f16* ab = sbuf + ((tt & 1) << 15);
    const f16* bb = ab + 16384;

    f16x8 a0[4], a1[4], bf[4];

    // ---- phase 0: kstep0, i-half0 (8 reads) ----
    RD_A(a0, 0, gk0);
    RD_B(bf, gk0);
    __builtin_amdgcn_s_barrier();
    asm volatile("s_waitcnt lgkmcnt(0)" ::: "memory");
    __builtin_amdgcn_sched_barrier(0);
    MFMA16(a0, bf, 0);
    __builtin_amdgcn_s_barrier();

    // ---- phase 1: kstep0, i-half1 (4 reads) ----
    RD_A(a1, 1, gk0);
    __builtin_amdgcn_s_barrier();
    asm volatile("s_waitcnt lgkmcnt(0)" ::: "memory");
    __builtin_amdgcn_sched_barrier(0);
    MFMA16(a1, bf, 1);
    __builtin_amdgcn_s_barrier();

    // ---- phase 2: kstep1, i-half0 (8 reads) ----
    RD_A(a0, 0, gk1);
    RD_B(bf, gk1);
    __builtin_amdgcn_s_barrier();
    asm volatile("s_waitcnt lgkmcnt(0)" ::: "memory");
    __builtin_amdgcn_sched_barrier(0);
    MFMA16(a0, bf, 0);
    __builtin_amdgcn_s_barrier();

    // ---- phase 3: kstep1, i-half1 (4 reads) + certify + stage t+2 ----
    RD_A(a1, 1, gk1);
    asm volatile("s_waitcnt lgkmcnt(0)" ::: "memory");  // my reads complete
    __builtin_amdgcn_sched_barrier(0);
    __builtin_amdgcn_s_barrier();      // ALL waves' reads of tile tt done
    __builtin_amdgcn_sched_barrier(0);
    if (tt < 14) STAGE(tt + 2);        // overwrite buf[tt&1] - now safe
    __builtin_amdgcn_sched_barrier(0);
    MFMA16(a1, bf, 1);
  }
#undef RD_A
#undef RD_B
#undef MFMA16
#undef STAGE

  // ---- epilogue: acc -> Cs[256][256] (XOR-swizzled) -> coalesced stores ----
  f16* Cs = sbuf;
  float bn[4];
#pragma unroll
  for (int j = 0; j < 4; ++j) bn[j] = bias[n0 + wc * 64 + j * 16 + fr];
#pragma unroll
  for (int i = 0; i < 8; ++i) {
#pragma unroll
    for (int j = 0; j < 4; ++j) {
#pragma unroll
      for (int v = 0; v < 4; ++v) {
        // C/D layout: col = lane&15, row = (lane>>4)*4 + v
        int row = wr * 128 + i * 16 + g * 4 + v;
        int col = wc * 64 + j * 16 + fr;
        Cs[row * 256 + (col ^ (((row >> 2) & 7) << 3))] =
            (f16)(acc[i][j][v] + bn[j]);
      }
    }
  }
  __syncthreads();

  const int rowMask = (1 << rowShift) - 1;
  const int row = t >> 1, half = t & 1;
  const int csw = ((row >> 2) & 7) << 3;
  const int arow = m0 + row;
  const int orow = (arow >> rowShift) * outStride + (arow & rowMask) + rowOff;
  f16* dst = C + (long long)orow * 1024 + n0 + half * 128;
  const f16* srcr = Cs + row * 256;
#pragma unroll
  for (int c = 0; c < 16; ++c)
    *(f16x8*)(dst + c * 8) = *(const f16x8*)(srcr + ((half * 128 + c * 8) ^ csw));
}

// ---------------------------------------------------------------------------
// All five projection GEMMs in ONE launch. 704 blocks = 8 * 88 (bijective
// XCD swizzle). v<512: K/V body GEMMs (M=16384); v>=512: Q-side (M=4096):
// z=0 -> Qh, z=1 -> Kh title rows, z=2 -> Vh title rows.
// ---------------------------------------------------------------------------
__global__ __launch_bounds__(512, 1) void gemm_all(
    const f16* __restrict__ Qb, const f16* __restrict__ Kb,
    const f16* __restrict__ Vb,
    const f16* __restrict__ Wqb, const f16* __restrict__ Wkb,
    const f16* __restrict__ Wvb,
    const float* __restrict__ bq, const float* __restrict__ bk,
    const float* __restrict__ bv,
    f16* __restrict__ Qh, f16* __restrict__ Kh, f16* __restrict__ Vh)
{
  __shared__ __align__(16) f16 sbuf[65536];   // 128 KiB
  const int bid = blockIdx.x;
  const int v = (bid & 7) * 88 + (bid >> 3);

  const f16* A;
  const f16* W;
  const float* bias;
  f16* C;
  int m0, n0, rowShift, outStride, rowOff;

  if (v < 512) {
    const int z = v >> 8, rem = v & 255;
    A = z ? Vb : Kb;
    W = z ? Wvb : Wkb;
    bias = z ? bv : bk;
    C = z ? Vh : Kh;
    m0 = (rem >> 2) * 256; n0 = (rem & 3) * 256;
    rowShift = 7; outStride = 160; rowOff = 0;
  } else {
    const int u = v - 512;
    const int z = u >> 6, rem = u & 63;
    A = Qb;
    W = (z == 0) ? Wqb : (z == 1) ? Wkb : Wvb;
    bias = (z == 0) ? bq : (z == 1) ? bk : bv;
    C = (z == 0) ? Qh : (z == 1) ? Kh : Vh;
    m0 = (rem >> 2) * 256; n0 = (rem & 3) * 256;
    rowShift = 5;
    outStride = (z == 0) ? 32 : 160;
    rowOff = (z == 0) ? 0 : 128;
  }
  gemm_tile_256(A, W, bias, C, m0, n0, rowShift, outStride, rowOff, sbuf);
}

// ---------------------------------------------------------------------------
// MFMA attention: one block per (b,h), 4 waves. (unchanged)
// ---------------------------------------------------------------------------
__global__ __launch_bounds__(256) void attn_kernel(
    const f16* __restrict__ Qh, const f16* __restrict__ Kh,
    const f16* __restrict__ Vh,
    const float* __restrict__ title, const float* __restrict__ body,
    float* __restrict__ out)
{
  __shared__ __align__(16) f16 Qs[32 * 72];    // stride 144B (b128-friendly)
  __shared__ __align__(16) f16 Ks[160 * 72];   // reused as Ps[32][168] (336B)
  __shared__ __align__(16) f16 Vs[160 * 68];   // stride 136B (2-way max on u16)
  __shared__ float rs[4][32];
  __shared__ float invs[32];

  const int bh = blockIdx.x, b = bh >> 4, h = bh & 15;
  const int t = threadIdx.x, w = t >> 6, lane = t & 63;
  const int c = lane & 15, g = lane >> 4;

  const long long qbase = ((long long)(b * 32) << 10) + h * 64;
  const long long kbase = ((long long)(b * 160) << 10) + h * 64;

  {
    int row = t >> 3, ch = t & 7;
    *(f16x8*)(Qs + row * 72 + ch * 8) =
        *(const f16x8*)(Qh + qbase + (long long)row * 1024 + ch * 8);
  }
#pragma unroll
  for (int r = 0; r < 5; ++r) {
    int i = t + r * 256;
    int row = i >> 3, ch = i & 7;
    *(f16x8*)(Ks + row * 72 + ch * 8) =
        *(const f16x8*)(Kh + kbase + (long long)row * 1024 + ch * 8);
    f16x8 vv = *(const f16x8*)(Vh + kbase + (long long)row * 1024 + ch * 8);
    f16x4 vlo = __builtin_shufflevector(vv, vv, 0, 1, 2, 3);
    f16x4 vhi = __builtin_shufflevector(vv, vv, 4, 5, 6, 7);
    *(f16x4*)(Vs + row * 68 + ch * 8) = vlo;
    *(f16x4*)(Vs + row * 68 + ch * 8 + 4) = vhi;
  }
  __syncthreads();

  f16x8 qf[2][2];
#pragma unroll
  for (int qt = 0; qt < 2; ++qt)
#pragma unroll
    for (int s = 0; s < 2; ++s)
      qf[qt][s] = *(const f16x8*)(Qs + (qt * 16 + c) * 72 + s * 32 + g * 8);

  const int cnt = (w < 2) ? 3 : 2;
  const int tile0 = (w < 2) ? w * 3 : 6 + (w - 2) * 2;

  f16x4 pp[3][2];
  float rsum[2] = {0.f, 0.f};

#pragma unroll
  for (int i = 0; i < 3; ++i) {
    if (i < cnt) {
      const int kt = tile0 + i;
      f16x8 kf0 = *(const f16x8*)(Ks + (kt * 16 + c) * 72 + 0 + g * 8);
      f16x8 kf1 = *(const f16x8*)(Ks + (kt * 16 + c) * 72 + 32 + g * 8);
#pragma unroll
      for (int qt = 0; qt < 2; ++qt) {
        f32x4v s4 = (f32x4v){0.f, 0.f, 0.f, 0.f};
        s4 = __builtin_amdgcn_mfma_f32_16x16x32_f16(kf0, qf[qt][0], s4, 0, 0, 0);
        s4 = __builtin_amdgcn_mfma_f32_16x16x32_f16(kf1, qf[qt][1], s4, 0, 0, 0);
        float4 m4;
        if (kt < 8) {
          m4 = *(const float4*)(body +
                ((long long)(b * 32 + qt * 16 + c)) * 128 + kt * 16 + 4 * g);
        } else {
          m4 = *(const float4*)(title + b * 32 + (kt - 8) * 16 + 4 * g);
        }
        float e0 = __expf(s4[0] * 0.125f) * m4.x;
        float e1 = __expf(s4[1] * 0.125f) * m4.y;
        float e2 = __expf(s4[2] * 0.125f) * m4.z;
        float e3 = __expf(s4[3] * 0.125f) * m4.w;
        rsum[qt] += (e0 + e1) + (e2 + e3);
        f16x4 p4;
        p4.x = (f16)e0; p4.y = (f16)e1; p4.z = (f16)e2; p4.w = (f16)e3;
        pp[i][qt] = p4;
      }
    }
  }

#pragma unroll
  for (int qt = 0; qt < 2; ++qt) {
    rsum[qt] += __shfl_xor(rsum[qt], 16);
    rsum[qt] += __shfl_xor(rsum[qt], 32);
  }
  if (lane < 16) {
    rs[w][c] = rsum[0];
    rs[w][16 + c] = rsum[1];
  }
  __syncthreads();

  f16* Ps = Ks;
#pragma unroll
  for (int i = 0; i < 3; ++i) {
    if (i < cnt) {
      const int kt = tile0 + i;
#pragma unroll
      for (int qt = 0; qt < 2; ++qt)
        *(f16x4*)(Ps + (qt * 16 + c) * 168 + kt * 16 + 4 * g) = pp[i][qt];
    }
  }
  if (t < 32) {
    float ssum = rs[0][t] + rs[1][t] + rs[2][t] + rs[3][t];
    invs[t] = title[b * 32 + t] / (ssum + 1e-8f);
  }
  __syncthreads();

  f32x4v o[2] = {(f32x4v){0.f, 0.f, 0.f, 0.f}, (f32x4v){0.f, 0.f, 0.f, 0.f}};
#pragma unroll
  for (int s = 0; s < 5; ++s) {
    f16x8 vf;
#pragma unroll
    for (int j = 0; j < 8; ++j)
      vf[j] = Vs[(32 * s + 8 * g + j) * 68 + 16 * w + c];
#pragma unroll
    for (int qt = 0; qt < 2; ++qt) {
      f16x8 pf = *(const f16x8*)(Ps + (qt * 16 + c) * 168 + s * 32 + g * 8);
      o[qt] = __builtin_amdgcn_mfma_f32_16x16x32_f16(pf, vf, o[qt], 0, 0, 0);
    }
  }

#pragma unroll
  for (int qt = 0; qt < 2; ++qt) {
#pragma unroll
    for (int v = 0; v < 4; ++v) {
      int q = qt * 16 + 4 * g + v;
      out[((long long)(b * 32 + q) << 10) + h * 64 + 16 * w + c] =
          o[qt][v] * invs[q];
    }
  }
}

// ---------------------------------------------------------------------------
extern "C" void kernel_launch(void* const* d_in, const int* in_sizes, int n_in,
                              void* d_out, int out_size, void* d_ws, size_t ws_size,
                              hipStream_t stream) {
  const float* Q_seq = (const float*)d_in[0];
  const float* K_seq = (const float*)d_in[1];
  const float* V_seq = (const float*)d_in[2];
  const float* title = (const float*)d_in[3];
  const float* body  = (const float*)d_in[4];
  const float* Wq = (const float*)d_in[5];
  const float* bq = (const float*)d_in[6];
  const float* Wk = (const float*)d_in[7];
  const float* bk = (const float*)d_in[8];
  const float* Wv = (const float*)d_in[9];
  const float* bv = (const float*)d_in[10];
  float* out = (float*)d_out;

  f16* ws = (f16*)d_ws;
  f16* Qb  = ws;
  f16* Kb  = Qb + 4194304;
  f16* Vb  = Kb + 16777216;
  f16* Wqb = Vb + 16777216;
  f16* Wkb = Wqb + 1048576;
  f16* Wvb = Wkb + 1048576;
  f16* Qh  = Wvb + 1048576;
  f16* Kh  = Qh + 4194304;
  f16* Vh  = Kh + 20971520;

  prep_kernel<<<19968, 256, 0, stream>>>(Q_seq, K_seq, V_seq, Wq, Wk, Wv,
                                         Qb, Kb, Vb, Wqb, Wkb, Wvb);
  gemm_all<<<704, 512, 0, stream>>>(Qb, Kb, Vb, Wqb, Wkb, Wvb,
                                    bq, bk, bv, Qh, Kh, Vh);
  attn_kernel<<<2048, 256, 0, stream>>>(Qh, Kh, Vh, title, body, out);
}

// Round 9
// 182.593 us; speedup vs baseline: 1.0371x; 1.0371x over previous
//
#include <hip/hip_runtime.h>

typedef _Float16 f16;
typedef _Float16 f16x2 __attribute__((ext_vector_type(2)));
typedef _Float16 f16x4 __attribute__((ext_vector_type(4)));
typedef _Float16 f16x8 __attribute__((ext_vector_type(8)));
typedef float f32x4v __attribute__((ext_vector_type(4)));

#define AS1 __attribute__((address_space(1)))
#define AS3 __attribute__((address_space(3)))

// async global->LDS, 16B per lane; LDS dest = wave-uniform base + lane*16
__device__ __forceinline__ void gload_lds16(const f16* g, f16* l) {
  __builtin_amdgcn_global_load_lds((const AS1 unsigned int*)g,
                                   (AS3 unsigned int*)l, 16, 0, 0);
}

// ---------------------------------------------------------------------------
// prep: fp32 -> fp16 conversions, 8 elems/thread (2x float4 -> 1x f16x8).
// ---------------------------------------------------------------------------
__global__ __launch_bounds__(256) void prep_kernel(
    const float* __restrict__ Q_seq, const float* __restrict__ K_seq,
    const float* __restrict__ V_seq,
    const float* __restrict__ Wq, const float* __restrict__ Wk,
    const float* __restrict__ Wv,
    f16* __restrict__ Qb, f16* __restrict__ Kb, f16* __restrict__ Vb,
    f16* __restrict__ Wqb, f16* __restrict__ Wkb, f16* __restrict__ Wvb)
{
  const long long g = (long long)blockIdx.x * 256 + threadIdx.x;
  const float* s;
  f16* d;
  if (g < 524288) {
    s = Q_seq + g * 8; d = Qb + g * 8;
  } else if (g < 2621440) {
    long long e = (g - 524288) * 8; s = K_seq + e; d = Kb + e;
  } else if (g < 4718592) {
    long long e = (g - 2621440) * 8; s = V_seq + e; d = Vb + e;
  } else if (g < 4849664) {
    long long e = (g - 4718592) * 8; s = Wq + e; d = Wqb + e;
  } else if (g < 4980736) {
    long long e = (g - 4849664) * 8; s = Wk + e; d = Wkb + e;
  } else {
    long long e = (g - 4980736) * 8; s = Wv + e; d = Wvb + e;
  }
  float4 v0 = *(const float4*)s;
  float4 v1 = *(const float4*)(s + 4);
  f16x8 o;
  o[0] = (f16)v0.x; o[1] = (f16)v0.y; o[2] = (f16)v0.z; o[3] = (f16)v0.w;
  o[4] = (f16)v1.x; o[5] = (f16)v1.y; o[6] = (f16)v1.z; o[7] = (f16)v1.w;
  *(f16x8*)d = o;
}

// ---------------------------------------------------------------------------
// 256x256 tile GEMM, BK=64, 8 waves (2M x 4N), double-buffered LDS (128 KiB).
// Minimal 2-phase schedule (T3 recipe, m230): per K-tile
//   { STAGE(t+1) ; [sched_barrier] ; plain ds_reads + MFMAs, COMPILER-
//     scheduled (fine-grained counted lgkmcnt interleave) ; __syncthreads }
// One barrier per tile. NO asm waitcnts, NO sched walls inside compute,
// NO setprio (null at 2-phase, m190). T2 read swizzle retained.
// Buffer safety: buf[(t+1)&1] was read at iter t-1, certified by its
// __syncthreads (per-wave lgkm drained before barrier). The STAGE DMA for
// t+1 completes before iter t+1's reads via this iter's vmcnt(0) drain in
// __syncthreads.
// ---------------------------------------------------------------------------
__device__ __forceinline__ void gemm_tile_256(
    const f16* __restrict__ A, const f16* __restrict__ W,
    const float* __restrict__ bias, f16* __restrict__ C,
    int m0, int n0, int rowShift, int outStride, int rowOff,
    f16* sbuf)
{
  const int t = threadIdx.x;
  const int w = t >> 6, lane = t & 63;
  const int wr = w >> 2, wc = w & 3;        // 2 x 4 wave grid
  const int fr = lane & 15, g = lane >> 4;  // fragment row / k-group
  const int lrow = lane >> 3;               // staging: row-in-8 block
  const int kgr = (lane & 7) ^ lrow;        // staging: pre-swizzled k-granule

  const f16* aSrc[4];
  const f16* bSrc[4];
#pragma unroll
  for (int s = 0; s < 4; ++s) {
    aSrc[s] = A + (long long)(m0 + (w * 4 + s) * 8 + lrow) * 1024 + kgr * 8;
    bSrc[s] = W + (long long)(n0 + (w * 4 + s) * 8 + lrow) * 1024 + kgr * 8;
  }

#define STAGE(tile)                                                          \
  {                                                                          \
    f16* ab_ = sbuf + (((tile) & 1) << 15);                                  \
    const int ko_ = (tile) * 64;                                             \
    _Pragma("unroll") for (int s = 0; s < 4; ++s)                            \
        gload_lds16(aSrc[s] + ko_, ab_ + (w * 4 + s) * 512);                 \
    _Pragma("unroll") for (int s = 0; s < 4; ++s)                            \
        gload_lds16(bSrc[s] + ko_, ab_ + 16384 + (w * 4 + s) * 512);         \
  }

  // fragment read offsets (f16 units), granule XOR-swizzled
  const int gk0 = ((0 + g) ^ (fr & 7)) * 8;   // k-half 0
  const int gk1 = ((4 + g) ^ (fr & 7)) * 8;   // k-half 1
  const int aoff = (wr * 128 + fr) * 64;
  const int boff = (wc * 64 + fr) * 64;

  f32x4v acc[8][4];
#pragma unroll
  for (int i = 0; i < 8; ++i)
#pragma unroll
    for (int j = 0; j < 4; ++j) acc[i][j] = (f32x4v){0.f, 0.f, 0.f, 0.f};

  STAGE(0);
  __syncthreads();   // buf0 resident (syncthreads drains vmcnt)

  for (int tt = 0; tt < 16; ++tt) {
    const f16* ab = sbuf + ((tt & 1) << 15);
    const f16* bb = ab + 16384;

    if (tt < 15) STAGE(tt + 1);           // other buffer, certified free
    __builtin_amdgcn_sched_barrier(0);    // pin DMA issue before compute

    // plain reads + MFMAs: compiler emits fine-grained counted lgkmcnt,
    // overlapping LDS service with MFMA issue (m97 mechanism).
    f16x8 a0[8], b0[4], a1[8], b1[4];
#pragma unroll
    for (int i = 0; i < 8; ++i)
      a0[i] = *(const f16x8*)(ab + aoff + i * 1024 + gk0);
#pragma unroll
    for (int j = 0; j < 4; ++j)
      b0[j] = *(const f16x8*)(bb + boff + j * 1024 + gk0);
#pragma unroll
    for (int i = 0; i < 8; ++i)
#pragma unroll
      for (int j = 0; j < 4; ++j)
        acc[i][j] = __builtin_amdgcn_mfma_f32_16x16x32_f16(a0[i], b0[j],
                                                           acc[i][j], 0, 0, 0);
#pragma unroll
    for (int i = 0; i < 8; ++i)
      a1[i] = *(const f16x8*)(ab + aoff + i * 1024 + gk1);
#pragma unroll
    for (int j = 0; j < 4; ++j)
      b1[j] = *(const f16x8*)(bb + boff + j * 1024 + gk1);
#pragma unroll
    for (int i = 0; i < 8; ++i)
#pragma unroll
      for (int j = 0; j < 4; ++j)
        acc[i][j] = __builtin_amdgcn_mfma_f32_16x16x32_f16(a1[i], b1[j],
                                                           acc[i][j], 0, 0, 0);

    __syncthreads();   // drains vmcnt(0)+lgkm(0): tile t+1 resident,
                       // all waves' reads of tile tt complete
  }
#undef STAGE

  // ---- epilogue: acc -> Cs[256][256] (XOR-swizzled) -> coalesced stores ----
  f16* Cs = sbuf;
  float bn[4];
#pragma unroll
  for (int j = 0; j < 4; ++j) bn[j] = bias[n0 + wc * 64 + j * 16 + fr];
#pragma unroll
  for (int i = 0; i < 8; ++i) {
#pragma unroll
    for (int j = 0; j < 4; ++j) {
#pragma unroll
      for (int v = 0; v < 4; ++v) {
        // C/D layout: col = lane&15, row = (lane>>4)*4 + v
        int row = wr * 128 + i * 16 + g * 4 + v;
        int col = wc * 64 + j * 16 + fr;
        Cs[row * 256 + (col ^ (((row >> 2) & 7) << 3))] =
            (f16)(acc[i][j][v] + bn[j]);
      }
    }
  }
  __syncthreads();

  const int rowMask = (1 << rowShift) - 1;
  const int row = t >> 1, half = t & 1;
  const int csw = ((row >> 2) & 7) << 3;
  const int arow = m0 + row;
  const int orow = (arow >> rowShift) * outStride + (arow & rowMask) + rowOff;
  f16* dst = C + (long long)orow * 1024 + n0 + half * 128;
  const f16* srcr = Cs + row * 256;
#pragma unroll
  for (int c = 0; c < 16; ++c)
    *(f16x8*)(dst + c * 8) = *(const f16x8*)(srcr + ((half * 128 + c * 8) ^ csw));
}

// ---------------------------------------------------------------------------
// All five projection GEMMs in ONE launch. 704 blocks = 8 * 88 (bijective
// XCD swizzle). v<512: K/V body GEMMs (M=16384); v>=512: Q-side (M=4096):
// z=0 -> Qh, z=1 -> Kh title rows, z=2 -> Vh title rows.
// ---------------------------------------------------------------------------
__global__ __launch_bounds__(512, 1) void gemm_all(
    const f16* __restrict__ Qb, const f16* __restrict__ Kb,
    const f16* __restrict__ Vb,
    const f16* __restrict__ Wqb, const f16* __restrict__ Wkb,
    const f16* __restrict__ Wvb,
    const float* __restrict__ bq, const float* __restrict__ bk,
    const float* __restrict__ bv,
    f16* __restrict__ Qh, f16* __restrict__ Kh, f16* __restrict__ Vh)
{
  __shared__ __align__(16) f16 sbuf[65536];   // 128 KiB
  const int bid = blockIdx.x;
  const int v = (bid & 7) * 88 + (bid >> 3);

  const f16* A;
  const f16* W;
  const float* bias;
  f16* C;
  int m0, n0, rowShift, outStride, rowOff;

  if (v < 512) {
    const int z = v >> 8, rem = v & 255;
    A = z ? Vb : Kb;
    W = z ? Wvb : Wkb;
    bias = z ? bv : bk;
    C = z ? Vh : Kh;
    m0 = (rem >> 2) * 256; n0 = (rem & 3) * 256;
    rowShift = 7; outStride = 160; rowOff = 0;
  } else {
    const int u = v - 512;
    const int z = u >> 6, rem = u & 63;
    A = Qb;
    W = (z == 0) ? Wqb : (z == 1) ? Wkb : Wvb;
    bias = (z == 0) ? bq : (z == 1) ? bk : bv;
    C = (z == 0) ? Qh : (z == 1) ? Kh : Vh;
    m0 = (rem >> 2) * 256; n0 = (rem & 3) * 256;
    rowShift = 5;
    outStride = (z == 0) ? 32 : 160;
    rowOff = (z == 0) ? 0 : 128;
  }
  gemm_tile_256(A, W, bias, C, m0, n0, rowShift, outStride, rowOff, sbuf);
}

// ---------------------------------------------------------------------------
// MFMA attention: one block per (b,h), 4 waves. (unchanged)
// ---------------------------------------------------------------------------
__global__ __launch_bounds__(256) void attn_kernel(
    const f16* __restrict__ Qh, const f16* __restrict__ Kh,
    const f16* __restrict__ Vh,
    const float* __restrict__ title, const float* __restrict__ body,
    float* __restrict__ out)
{
  __shared__ __align__(16) f16 Qs[32 * 72];    // stride 144B (b128-friendly)
  __shared__ __align__(16) f16 Ks[160 * 72];   // reused as Ps[32][168] (336B)
  __shared__ __align__(16) f16 Vs[160 * 68];   // stride 136B (2-way max on u16)
  __shared__ float rs[4][32];
  __shared__ float invs[32];

  const int bh = blockIdx.x, b = bh >> 4, h = bh & 15;
  const int t = threadIdx.x, w = t >> 6, lane = t & 63;
  const int c = lane & 15, g = lane >> 4;

  const long long qbase = ((long long)(b * 32) << 10) + h * 64;
  const long long kbase = ((long long)(b * 160) << 10) + h * 64;

  {
    int row = t >> 3, ch = t & 7;
    *(f16x8*)(Qs + row * 72 + ch * 8) =
        *(const f16x8*)(Qh + qbase + (long long)row * 1024 + ch * 8);
  }
#pragma unroll
  for (int r = 0; r < 5; ++r) {
    int i = t + r * 256;
    int row = i >> 3, ch = i & 7;
    *(f16x8*)(Ks + row * 72 + ch * 8) =
        *(const f16x8*)(Kh + kbase + (long long)row * 1024 + ch * 8);
    f16x8 vv = *(const f16x8*)(Vh + kbase + (long long)row * 1024 + ch * 8);
    f16x4 vlo = __builtin_shufflevector(vv, vv, 0, 1, 2, 3);
    f16x4 vhi = __builtin_shufflevector(vv, vv, 4, 5, 6, 7);
    *(f16x4*)(Vs + row * 68 + ch * 8) = vlo;
    *(f16x4*)(Vs + row * 68 + ch * 8 + 4) = vhi;
  }
  __syncthreads();

  f16x8 qf[2][2];
#pragma unroll
  for (int qt = 0; qt < 2; ++qt)
#pragma unroll
    for (int s = 0; s < 2; ++s)
      qf[qt][s] = *(const f16x8*)(Qs + (qt * 16 + c) * 72 + s * 32 + g * 8);

  const int cnt = (w < 2) ? 3 : 2;
  const int tile0 = (w < 2) ? w * 3 : 6 + (w - 2) * 2;

  f16x4 pp[3][2];
  float rsum[2] = {0.f, 0.f};

#pragma unroll
  for (int i = 0; i < 3; ++i) {
    if (i < cnt) {
      const int kt = tile0 + i;
      f16x8 kf0 = *(const f16x8*)(Ks + (kt * 16 + c) * 72 + 0 + g * 8);
      f16x8 kf1 = *(const f16x8*)(Ks + (kt * 16 + c) * 72 + 32 + g * 8);
#pragma unroll
      for (int qt = 0; qt < 2; ++qt) {
        f32x4v s4 = (f32x4v){0.f, 0.f, 0.f, 0.f};
        s4 = __builtin_amdgcn_mfma_f32_16x16x32_f16(kf0, qf[qt][0], s4, 0, 0, 0);
        s4 = __builtin_amdgcn_mfma_f32_16x16x32_f16(kf1, qf[qt][1], s4, 0, 0, 0);
        float4 m4;
        if (kt < 8) {
          m4 = *(const float4*)(body +
                ((long long)(b * 32 + qt * 16 + c)) * 128 + kt * 16 + 4 * g);
        } else {
          m4 = *(const float4*)(title + b * 32 + (kt - 8) * 16 + 4 * g);
        }
        float e0 = __expf(s4[0] * 0.125f) * m4.x;
        float e1 = __expf(s4[1] * 0.125f) * m4.y;
        float e2 = __expf(s4[2] * 0.125f) * m4.z;
        float e3 = __expf(s4[3] * 0.125f) * m4.w;
        rsum[qt] += (e0 + e1) + (e2 + e3);
        f16x4 p4;
        p4.x = (f16)e0; p4.y = (f16)e1; p4.z = (f16)e2; p4.w = (f16)e3;
        pp[i][qt] = p4;
      }
    }
  }

#pragma unroll
  for (int qt = 0; qt < 2; ++qt) {
    rsum[qt] += __shfl_xor(rsum[qt], 16);
    rsum[qt] += __shfl_xor(rsum[qt], 32);
  }
  if (lane < 16) {
    rs[w][c] = rsum[0];
    rs[w][16 + c] = rsum[1];
  }
  __syncthreads();

  f16* Ps = Ks;
#pragma unroll
  for (int i = 0; i < 3; ++i) {
    if (i < cnt) {
      const int kt = tile0 + i;
#pragma unroll
      for (int qt = 0; qt < 2; ++qt)
        *(f16x4*)(Ps + (qt * 16 + c) * 168 + kt * 16 + 4 * g) = pp[i][qt];
    }
  }
  if (t < 32) {
    float ssum = rs[0][t] + rs[1][t] + rs[2][t] + rs[3][t];
    invs[t] = title[b * 32 + t] / (ssum + 1e-8f);
  }
  __syncthreads();

  f32x4v o[2] = {(f32x4v){0.f, 0.f, 0.f, 0.f}, (f32x4v){0.f, 0.f, 0.f, 0.f}};
#pragma unroll
  for (int s = 0; s < 5; ++s) {
    f16x8 vf;
#pragma unroll
    for (int j = 0; j < 8; ++j)
      vf[j] = Vs[(32 * s + 8 * g + j) * 68 + 16 * w + c];
#pragma unroll
    for (int qt = 0; qt < 2; ++qt) {
      f16x8 pf = *(const f16x8*)(Ps + (qt * 16 + c) * 168 + s * 32 + g * 8);
      o[qt] = __builtin_amdgcn_mfma_f32_16x16x32_f16(pf, vf, o[qt], 0, 0, 0);
    }
  }

#pragma unroll
  for (int qt = 0; qt < 2; ++qt) {
#pragma unroll
    for (int v = 0; v < 4; ++v) {
      int q = qt * 16 + 4 * g + v;
      out[((long long)(b * 32 + q) << 10) + h * 64 + 16 * w + c] =
          o[qt][v] * invs[q];
    }
  }
}

// ---------------------------------------------------------------------------
extern "C" void kernel_launch(void* const* d_in, const int* in_sizes, int n_in,
                              void* d_out, int out_size, void* d_ws, size_t ws_size,
                              hipStream_t stream) {
  const float* Q_seq = (const float*)d_in[0];
  const float* K_seq = (const float*)d_in[1];
  const float* V_seq = (const float*)d_in[2];
  const float* title = (const float*)d_in[3];
  const float* body  = (const float*)d_in[4];
  const float* Wq = (const float*)d_in[5];
  const float* bq = (const float*)d_in[6];
  const float* Wk = (const float*)d_in[7];
  const float* bk = (const float*)d_in[8];
  const float* Wv = (const float*)d_in[9];
  const float* bv = (const float*)d_in[10];
  float* out = (float*)d_out;

  f16* ws = (f16*)d_ws;
  f16* Qb  = ws;
  f16* Kb  = Qb + 4194304;
  f16* Vb  = Kb + 16777216;
  f16* Wqb = Vb + 16777216;
  f16* Wkb = Wqb + 1048576;
  f16* Wvb = Wkb + 1048576;
  f16* Qh  = Wvb + 1048576;
  f16* Kh  = Qh + 4194304;
  f16* Vh  = Kh + 20971520;

  prep_kernel<<<19968, 256, 0, stream>>>(Q_seq, K_seq, V_seq, Wq, Wk, Wv,
                                         Qb, Kb, Vb, Wqb, Wkb, Wvb);
  gemm_all<<<704, 512, 0, stream>>>(Qb, Kb, Vb, Wqb, Wkb, Wvb,
                                    bq, bk, bv, Qh, Kh, Vh);
  attn_kernel<<<2048, 256, 0, stream>>>(Qh, Kh, Vh, title, body, out);
}